// Round 1
// baseline (793.586 us; speedup 1.0000x reference)
//
#include <hip/hip_runtime.h>
#include <cmath>

#define NS 51
#define ND 50
#define PLANE 1048576            // 1024*1024
#define DOG_ELEMS (ND * PLANE)   // 52428800
#define WPSTRIDE 144             // padded 1-D kernel: 16 zeros | up to 103 taps | zeros

// ---------------- K0: extract normalized 1-D kernels + radii from 2-D weight ----
__global__ void dog_prep(const float* __restrict__ weight,
                         float* __restrict__ wp,
                         int* __restrict__ rarr, int S) {
    int i = blockIdx.x;
    int R = (S - 1) >> 1;
    const float* row = weight + ((size_t)i * S + R) * S;   // center row of scale i
    int t = threadIdx.x;
    for (int j = t; j < WPSTRIDE; j += blockDim.x) wp[i * WPSTRIDE + j] = 0.f;
    __syncthreads();
    if (t == 0) {
        float sum = 0.f;
        for (int j = 0; j < S; ++j) sum += row[j];
        int pad = 0;
        while (pad < R && row[pad] == 0.f) ++pad;
        int r = R - pad;
        rarr[i] = r;
        for (int j = 0; j <= 2 * r; ++j)
            wp[i * WPSTRIDE + 16 + j] = row[pad + j] / sum;
    }
}

// ---------------- K1: horizontal blur, one row per block ------------------------
// thread t -> outputs x = 4t..4t+3 (float4 store). m-loop: 1 LDS read + 4 FMA/tap,
// rolling uniform weights (SGPR). LDS row stored 4-way interleaved (stride 289,
// 289%32==1) so the stride-4 read pattern is bank-conflict-free.
__global__ __launch_bounds__(256) void dog_hblur(
        const float* __restrict__ in, float* __restrict__ tmpH,
        const float* __restrict__ wp, const int* __restrict__ rarr) {
    int y = blockIdx.x;
    int i = blockIdx.y;
    int t = threadIdx.x;
    int r = rarr[i];
    const float* __restrict__ w = wp + i * WPSTRIDE;
    __shared__ float srow[4 * 289];
    const float* inrow = in + ((size_t)y << 10);
    for (int j = t; j < 1126; j += 256) {           // x in [-51, 1075)
        int x = j - 51;
        float v = (x >= 0 && x < 1024) ? inrow[x] : 0.f;
        srow[(j & 3) * 289 + (j >> 2)] = v;
    }
    __syncthreads();
    float a0 = 0.f, a1 = 0.f, a2 = 0.f, a3 = 0.f;
    float w0 = 0.f, w1 = 0.f, w2 = 0.f, w3 = 0.f;
    int mmax = 2 * r + 3;
    int u0 = 51 - r;
    for (int m = 0; m <= mmax; ++m) {
        w3 = w2; w2 = w1; w1 = w0; w0 = w[16 + m];  // uniform -> s_load/SGPR
        int u = u0 + m;                              // j = 4t + u
        float v = srow[(u & 3) * 289 + (u >> 2) + t];
        a0 = fmaf(w0, v, a0);
        a1 = fmaf(w1, v, a1);
        a2 = fmaf(w2, v, a2);
        a3 = fmaf(w3, v, a3);
    }
    float4 o = make_float4(a0, a1, a2, a3);
    *(float4*)(tmpH + (((size_t)i) << 20) + ((size_t)y << 10) + 4 * t) = o;
}

// ---------------- K2: vertical blur + DoG, fused over a scale chunk -------------
// block: 64x64 tile, 256 threads (tx 0..63, 4 row-groups of 16 rows).
// Per scale: stage (64+2r)x64 tmpH tile in LDS, 16 accumulators/thread,
// m-loop with rolling 16 uniform weights; dog_j = (g_j - g_{j+1})*sigma_j.
__global__ __launch_bounds__(256) void dog_vblur(
        const float* __restrict__ tmpH, float* __restrict__ dog,
        const float* __restrict__ wp, const int* __restrict__ rarr,
        const float* __restrict__ sigmas) {
    int x0 = blockIdx.x << 6;
    int y0 = blockIdx.y << 6;
    int i0 = blockIdx.z * 10;
    int t = threadIdx.x;
    int tx = t & 63, tg = t >> 6;
    __shared__ float tile[166 * 64];
    float gprev[16];
#pragma unroll
    for (int k = 0; k < 16; ++k) gprev[k] = 0.f;
    for (int s = 0; s <= 10; ++s) {
        int i = i0 + s;
        int r = rarr[i];
        int nelem = (64 + 2 * r) << 6;
        for (int e = t; e < nelem; e += 256) {
            int gy = y0 - r + (e >> 6);
            tile[e] = (gy >= 0 && gy < 1024)
                    ? tmpH[(((size_t)i) << 20) + ((size_t)gy << 10) + x0 + (e & 63)]
                    : 0.f;
        }
        __syncthreads();
        const float* __restrict__ w = wp + i * WPSTRIDE;
        float acc[16];
        float W[16];
#pragma unroll
        for (int k = 0; k < 16; ++k) { acc[k] = 0.f; W[k] = 0.f; }
        int mmax = 2 * r + 15;
        int base = (tg << 10) | tx;                 // row tg*16, col tx
        for (int m = 0; m <= mmax; ++m) {
#pragma unroll
            for (int k = 15; k >= 1; --k) W[k] = W[k - 1];
            W[0] = w[16 + m];                       // uniform -> SGPR
            float v = tile[base + (m << 6)];
#pragma unroll
            for (int k = 0; k < 16; ++k) acc[k] = fmaf(W[k], v, acc[k]);
        }
        __syncthreads();                            // LDS reads done before restage
        if (s >= 1) {
            int j = i - 1;
            float sg = sigmas[j];
            size_t ob = (((size_t)j) << 20) + ((size_t)(y0 + (tg << 4)) << 10) + x0 + tx;
#pragma unroll
            for (int k = 0; k < 16; ++k)
                dog[ob + ((size_t)k << 10)] = (gprev[k] - acc[k]) * sg;
        }
#pragma unroll
        for (int k = 0; k < 16; ++k) gprev[k] = acc[k];
    }
}

// ---------------- K3: 3x3x3 max-pool + outputs, ring-buffered over scale --------
// block: 64x16 tile. D ring (3 x 18x66, -inf padded), M ring (3 x 16x64 = 3x3 xy-max).
// pooled_j = max(M_{j-1}, M_j, M_{j+1}); lm = relu(pooled+thr); sm = 1-lm+dog+thr.
__global__ __launch_bounds__(256) void dog_pool(
        const float* __restrict__ dog, float* __restrict__ out,
        const float* __restrict__ thr_p) {
    int x0 = blockIdx.x << 6;
    int y0 = blockIdx.y << 4;
    int t = threadIdx.x;
    float thr = thr_p[0];
    __shared__ float D[3][18 * 66];
    __shared__ float M[3][1024];
    const float NEG = -__builtin_huge_valf();
    for (int i = 0; i < ND; ++i) {
        float* Dt = D[i % 3];
        for (int e = t; e < 18 * 66; e += 256) {
            int row = e / 66, col = e - row * 66;
            int gy = y0 - 1 + row, gx = x0 - 1 + col;
            Dt[e] = (gy >= 0 && gy < 1024 && gx >= 0 && gx < 1024)
                  ? dog[(((size_t)i) << 20) + ((size_t)gy << 10) + gx] : NEG;
        }
        __syncthreads();
        float* Mt = M[i % 3];
#pragma unroll
        for (int q = 0; q < 4; ++q) {
            int e = t + (q << 8);
            int yy = e >> 6, xx = e & 63;
            const float* p = Dt + yy * 66 + xx;
            float mx = p[0];
            mx = fmaxf(mx, p[1]);   mx = fmaxf(mx, p[2]);
            mx = fmaxf(mx, p[66]);  mx = fmaxf(mx, p[67]);  mx = fmaxf(mx, p[68]);
            mx = fmaxf(mx, p[132]); mx = fmaxf(mx, p[133]); mx = fmaxf(mx, p[134]);
            Mt[e] = mx;
        }
        __syncthreads();
        if (i >= 1) {
            int j = i - 1;
            const float* Mj  = M[j % 3];
            const float* Mjm = M[(j + 2) % 3];
            const float* Mjp = M[(j + 1) % 3];
            const float* Dj  = D[j % 3];
            size_t ob = (((size_t)j) << 20) + ((size_t)y0 << 10) + x0;
#pragma unroll
            for (int q = 0; q < 4; ++q) {
                int e = t + (q << 8);
                int yy = e >> 6, xx = e & 63;
                float p = fmaxf(Mj[e], Mjp[e]);
                if (j >= 1) p = fmaxf(p, Mjm[e]);
                float dval = Dj[(yy + 1) * 66 + xx + 1];
                float lm = fmaxf(p + thr, 0.f);
                float sm = 1.f - lm + dval + thr;
                size_t idx = ob + ((size_t)yy << 10) + xx;
                out[idx] = lm;
                out[DOG_ELEMS + idx] = sm;
            }
        }
    }
    {   // tail: j = 49 (M_50 = -inf)
        int j = ND - 1;
        const float* Mj  = M[j % 3];
        const float* Mjm = M[(j + 2) % 3];
        const float* Dj  = D[j % 3];
        size_t ob = (((size_t)j) << 20) + ((size_t)y0 << 10) + x0;
#pragma unroll
        for (int q = 0; q < 4; ++q) {
            int e = t + (q << 8);
            int yy = e >> 6, xx = e & 63;
            float p = fmaxf(Mj[e], Mjm[e]);
            float dval = Dj[(yy + 1) * 66 + xx + 1];
            float lm = fmaxf(p + thr, 0.f);
            float sm = 1.f - lm + dval + thr;
            size_t idx = ob + ((size_t)yy << 10) + xx;
            out[idx] = lm;
            out[DOG_ELEMS + idx] = sm;
        }
    }
}

extern "C" void kernel_launch(void* const* d_in, const int* in_sizes, int n_in,
                              void* d_out, int out_size, void* d_ws, size_t ws_size,
                              hipStream_t stream) {
    const float* input  = (const float*)d_in[0];
    const float* weight = (const float*)d_in[1];
    const float* sigmas = (const float*)d_in[2];
    const float* thr    = (const float*)d_in[3];
    float* out = (float*)d_out;

    int S = 103;
    if (n_in > 1 && in_sizes[1] >= NS) {
        int s2 = in_sizes[1] / NS;
        S = (int)(sqrt((double)s2) + 0.5);
    }

    size_t need = (size_t)DOG_ELEMS * 4 + (size_t)NS * WPSTRIDE * 4 + NS * 4 + 256;
    if (ws_size < need) return;   // insufficient scratch -> visible validation failure

    float* dogbuf = (float*)d_ws;                  // 50 * 1M floats (210 MB)
    float* wp     = dogbuf + DOG_ELEMS;            // 51 * 144 floats
    int*   rarr   = (int*)(wp + NS * WPSTRIDE);    // 51 ints
    float* tmpH   = out;                           // 51 planes, dead before K3 writes

    dog_prep <<<NS, 128, 0, stream>>>(weight, wp, rarr, S);
    dog_hblur<<<dim3(1024, NS), 256, 0, stream>>>(input, tmpH, wp, rarr);
    dog_vblur<<<dim3(16, 16, 5), 256, 0, stream>>>(tmpH, dogbuf, wp, rarr, sigmas);
    dog_pool <<<dim3(16, 64), 256, 0, stream>>>(dogbuf, out, thr);
}

// Round 2
// 548.389 us; speedup vs baseline: 1.4471x; 1.4471x over previous
//
#include <hip/hip_runtime.h>
#include <cmath>

#define NS 51
#define ND 50
#define PLANE 1048576            // 1024*1024
#define DOG_ELEMS (ND * PLANE)   // 52428800
#define WPSTRIDE 144             // padded 1-D kernel: 16 zeros | taps | zeros

// ---------------- K0: extract normalized 1-D kernels + radii from 2-D weight ----
__global__ void dog_prep(const float* __restrict__ weight,
                         float* __restrict__ wp,
                         int* __restrict__ rarr, int S) {
    int i = blockIdx.x;
    int R = (S - 1) >> 1;
    const float* row = weight + ((size_t)i * S + R) * S;   // center row of scale i
    int t = threadIdx.x;
    for (int j = t; j < WPSTRIDE; j += blockDim.x) wp[i * WPSTRIDE + j] = 0.f;
    __syncthreads();
    if (t == 0) {
        float sum = 0.f;
        for (int j = 0; j < S; ++j) sum += row[j];
        int pad = 0;
        while (pad < R && row[pad] == 0.f) ++pad;
        int r = R - pad;
        rarr[i] = r;
        for (int j = 0; j <= 2 * r; ++j)
            wp[i * WPSTRIDE + 16 + j] = row[pad + j] / sum;
    }
}

// ---------------- K1: horizontal blur -------------------------------------------
// 2 rows/block (2 groups x 128 threads), 8 outputs/thread. LDS row 8-way
// interleaved (stride 143, odd) so stride-8 reads are conflict-free. m-loop
// unrolled x8 with static weight indexing (no register shift).
__global__ __launch_bounds__(256) void dog_hblur(
        const float* __restrict__ in, float* __restrict__ tmpH,
        const float* __restrict__ wp, const int* __restrict__ rarr) {
    int i = blockIdx.y;
    int t = threadIdx.x;
    int grp = t >> 7;
    int tl = t & 127;
    int y = (blockIdx.x << 1) | grp;
    int r = rarr[i];
    const float* __restrict__ w = wp + i * WPSTRIDE;
    __shared__ float srow[2][1144];                 // 8 phases x 143
    const float* inrow = in + ((size_t)y << 10);
    for (int j = tl; j < 1144; j += 128) {          // x in [-56, 1088)
        int x = j - 56;
        srow[grp][(j & 7) * 143 + (j >> 3)] = (x >= 0 && x < 1024) ? inrow[x] : 0.f;
    }
    __syncthreads();
    float acc[8];
#pragma unroll
    for (int k = 0; k < 8; ++k) acc[k] = 0.f;
    int c0 = 56 - r;                                // >= 5
    int mcount = ((2 * r + 15) >> 3) << 3;          // covers mm=0..2r+7
    const float* s = srow[grp];
    for (int m = 0; m < mcount; m += 8) {
        float v[8];
#pragma unroll
        for (int j2 = 0; j2 < 8; ++j2) {
            int q = m + j2 + c0;                    // uniform
            v[j2] = s[(q & 7) * 143 + tl + (q >> 3)];
        }
#pragma unroll
        for (int j2 = 0; j2 < 8; ++j2)
#pragma unroll
            for (int k = 0; k < 8; ++k)
                acc[k] = fmaf(w[16 + m + j2 - k], v[j2], acc[k]);
    }
    float* o = tmpH + (((size_t)i) << 20) + ((size_t)y << 10) + (tl << 3);
    *(float4*)o       = make_float4(acc[0], acc[1], acc[2], acc[3]);
    *(float4*)(o + 4) = make_float4(acc[4], acc[5], acc[6], acc[7]);
}

// ---------------- K2: vertical blur + DoG ---------------------------------------
// 64x32 tile, 256 threads (4 groups x 8 rows). float4 staging, m-loop unrolled
// x8 with static weight indexing. LDS 34.8 KB -> 4 blocks/CU.
__global__ __launch_bounds__(256) void dog_vblur(
        const float* __restrict__ tmpH, float* __restrict__ dog,
        const float* __restrict__ wp, const int* __restrict__ rarr,
        const float* __restrict__ sigmas) {
    int x0 = blockIdx.x << 6;
    int y0 = blockIdx.y << 5;
    int i0 = blockIdx.z * 10;
    int t = threadIdx.x;
    int tx = t & 63, tg = t >> 6;
    __shared__ float tile[136 * 64];
    float gprev[8];
#pragma unroll
    for (int k = 0; k < 8; ++k) gprev[k] = 0.f;
    for (int s = 0; s <= 10; ++s) {
        int i = i0 + s;
        int r = rarr[i];
        int mcount = ((2 * r + 15) >> 3) << 3;      // mult of 8, covers 2r+8 iters
        int nstage = mcount + 24;                   // rows staged (<= 136)
        int n4 = nstage << 4;                       // float4 count (16 per row)
        for (int e = t; e < n4; e += 256) {
            int row = e >> 4;
            int gy = y0 - r + row;
            float4 v = make_float4(0.f, 0.f, 0.f, 0.f);
            if (gy >= 0 && gy < 1024)
                v = *(const float4*)(tmpH + (((size_t)i) << 20) + ((size_t)gy << 10)
                                     + x0 + ((e & 15) << 2));
            ((float4*)tile)[e] = v;
        }
        __syncthreads();
        const float* __restrict__ w = wp + i * WPSTRIDE;
        float acc[8];
#pragma unroll
        for (int k = 0; k < 8; ++k) acc[k] = 0.f;
        int base = (tg << 9) + tx;                  // row tg*8, col tx
        for (int m = 0; m < mcount; m += 8) {
            float v[8];
#pragma unroll
            for (int j = 0; j < 8; ++j) v[j] = tile[base + ((m + j) << 6)];
#pragma unroll
            for (int j = 0; j < 8; ++j)
#pragma unroll
                for (int k = 0; k < 8; ++k)
                    acc[k] = fmaf(w[16 + m + j - k], v[j], acc[k]);
        }
        __syncthreads();
        if (s >= 1) {
            int j = i - 1;
            float sg = sigmas[j];
            size_t ob = (((size_t)j) << 20) + ((size_t)(y0 + (tg << 3)) << 10) + x0 + tx;
#pragma unroll
            for (int k = 0; k < 8; ++k)
                dog[ob + ((size_t)k << 10)] = (gprev[k] - acc[k]) * sg;
        }
#pragma unroll
        for (int k = 0; k < 8; ++k) gprev[k] = acc[k];
    }
}

// ---------------- K3: 3x3x3 max-pool + outputs ----------------------------------
// 64x16 tile; thread -> 4 consecutive x (all LDS traffic & stores are float4).
// D ring: 3 x 18 rows x 72 (covers x0-4..x0+67, -inf padded).
// M ring: 3 x 18 rows x 68 (row-wise 3-max). pooled = max over 3 scales x 3 rows.
#define DST 72
#define MST 68
__global__ __launch_bounds__(256) void dog_pool(
        const float* __restrict__ dog, float* __restrict__ out,
        const float* __restrict__ thr_p) {
    int x0 = blockIdx.x << 6;
    int y0 = blockIdx.y << 4;
    int t = threadIdx.x;
    int xq = t & 15, yy = t >> 4;
    float thr = thr_p[0];
    __shared__ float D[3][18 * DST];
    __shared__ float M[3][18 * MST];
    const float NEG = -__builtin_huge_valf();
    for (int ii = 0; ii < ND; ++ii) {
        float* Dt = D[ii % 3];
        for (int f = t; f < 324; f += 256) {        // 18 rows x 18 float4
            int row = f / 18, c = f - row * 18;
            int gy = y0 - 1 + row;
            int gx = x0 - 4 + (c << 2);             // always mult of 4
            float4 v = make_float4(NEG, NEG, NEG, NEG);
            if (gy >= 0 && gy < 1024 && gx >= 0 && gx < 1024)
                v = *(const float4*)(dog + (((size_t)ii) << 20) + ((size_t)gy << 10) + gx);
            *(float4*)&Dt[row * DST + (c << 2)] = v;
        }
        __syncthreads();
        float* Mt = M[ii % 3];
        for (int f = t; f < 288; f += 256) {        // 18 rows x 16 float4
            int row = f >> 4, c = f & 15;
            const float* p = &Dt[row * DST + (c << 2)];
            float4 a  = *(const float4*)p;          // cols 4c..4c+3
            float4 b  = *(const float4*)(p + 4);    // 4c+4..4c+7
            float4 cc = *(const float4*)(p + 8);    // 4c+8..4c+11
            float4 m;
            m.x = fmaxf(fmaxf(a.w, b.x), b.y);
            m.y = fmaxf(fmaxf(b.x, b.y), b.z);
            m.z = fmaxf(fmaxf(b.y, b.z), b.w);
            m.w = fmaxf(fmaxf(b.z, b.w), cc.x);
            *(float4*)&Mt[row * MST + (c << 2)] = m;
        }
        __syncthreads();
        if (ii >= 1) {
            int j = ii - 1;
            const float* Mj  = M[j % 3];
            const float* Mjp = M[(j + 1) % 3];
            const float* Mjm = M[(j + 2) % 3];
            float4 p4 = make_float4(NEG, NEG, NEG, NEG);
#pragma unroll
            for (int d = 0; d < 3; ++d) {
                int off = (yy + d) * MST + (xq << 2);
                float4 u  = *(const float4*)&Mj[off];
                float4 w2 = *(const float4*)&Mjp[off];
                p4.x = fmaxf(p4.x, fmaxf(u.x, w2.x));
                p4.y = fmaxf(p4.y, fmaxf(u.y, w2.y));
                p4.z = fmaxf(p4.z, fmaxf(u.z, w2.z));
                p4.w = fmaxf(p4.w, fmaxf(u.w, w2.w));
                if (j >= 1) {
                    float4 z = *(const float4*)&Mjm[off];
                    p4.x = fmaxf(p4.x, z.x); p4.y = fmaxf(p4.y, z.y);
                    p4.z = fmaxf(p4.z, z.z); p4.w = fmaxf(p4.w, z.w);
                }
            }
            float4 dv = *(const float4*)&D[j % 3][(yy + 1) * DST + 4 + (xq << 2)];
            float4 lm, sm;
            lm.x = fmaxf(p4.x + thr, 0.f); lm.y = fmaxf(p4.y + thr, 0.f);
            lm.z = fmaxf(p4.z + thr, 0.f); lm.w = fmaxf(p4.w + thr, 0.f);
            sm.x = 1.f - lm.x + dv.x + thr; sm.y = 1.f - lm.y + dv.y + thr;
            sm.z = 1.f - lm.z + dv.z + thr; sm.w = 1.f - lm.w + dv.w + thr;
            size_t idx = (((size_t)j) << 20) + ((size_t)(y0 + yy) << 10) + x0 + (xq << 2);
            *(float4*)&out[idx] = lm;
            *(float4*)&out[DOG_ELEMS + idx] = sm;
        }
    }
    {   // tail: j = 49 (scale 50 pooled plane = -inf)
        int j = ND - 1;
        const float* Mj  = M[j % 3];
        const float* Mjm = M[(j + 2) % 3];
        float4 p4 = make_float4(NEG, NEG, NEG, NEG);
#pragma unroll
        for (int d = 0; d < 3; ++d) {
            int off = (yy + d) * MST + (xq << 2);
            float4 u = *(const float4*)&Mj[off];
            float4 z = *(const float4*)&Mjm[off];
            p4.x = fmaxf(p4.x, fmaxf(u.x, z.x));
            p4.y = fmaxf(p4.y, fmaxf(u.y, z.y));
            p4.z = fmaxf(p4.z, fmaxf(u.z, z.z));
            p4.w = fmaxf(p4.w, fmaxf(u.w, z.w));
        }
        float4 dv = *(const float4*)&D[j % 3][(yy + 1) * DST + 4 + (xq << 2)];
        float4 lm, sm;
        lm.x = fmaxf(p4.x + thr, 0.f); lm.y = fmaxf(p4.y + thr, 0.f);
        lm.z = fmaxf(p4.z + thr, 0.f); lm.w = fmaxf(p4.w + thr, 0.f);
        sm.x = 1.f - lm.x + dv.x + thr; sm.y = 1.f - lm.y + dv.y + thr;
        sm.z = 1.f - lm.z + dv.z + thr; sm.w = 1.f - lm.w + dv.w + thr;
        size_t idx = (((size_t)j) << 20) + ((size_t)(y0 + yy) << 10) + x0 + (xq << 2);
        *(float4*)&out[idx] = lm;
        *(float4*)&out[DOG_ELEMS + idx] = sm;
    }
}

extern "C" void kernel_launch(void* const* d_in, const int* in_sizes, int n_in,
                              void* d_out, int out_size, void* d_ws, size_t ws_size,
                              hipStream_t stream) {
    const float* input  = (const float*)d_in[0];
    const float* weight = (const float*)d_in[1];
    const float* sigmas = (const float*)d_in[2];
    const float* thr    = (const float*)d_in[3];
    float* out = (float*)d_out;

    int S = 103;
    if (n_in > 1 && in_sizes[1] >= NS) {
        int s2 = in_sizes[1] / NS;
        S = (int)(sqrt((double)s2) + 0.5);
    }

    size_t need = (size_t)DOG_ELEMS * 4 + (size_t)NS * WPSTRIDE * 4 + NS * 4 + 256;
    if (ws_size < need) return;   // insufficient scratch -> visible validation failure

    float* dogbuf = (float*)d_ws;                  // 50 * 1M floats (210 MB)
    float* wp     = dogbuf + DOG_ELEMS;            // 51 * 144 floats
    int*   rarr   = (int*)(wp + NS * WPSTRIDE);    // 51 ints
    float* tmpH   = out;                           // 51 planes in d_out, dead before K3 writes

    dog_prep <<<NS, 128, 0, stream>>>(weight, wp, rarr, S);
    dog_hblur<<<dim3(512, NS), 256, 0, stream>>>(input, tmpH, wp, rarr);
    dog_vblur<<<dim3(16, 32, 5), 256, 0, stream>>>(tmpH, dogbuf, wp, rarr, sigmas);
    dog_pool <<<dim3(16, 64), 256, 0, stream>>>(dogbuf, out, thr);
}